// Round 6
// baseline (190.277 us; speedup 1.0000x reference)
//
#include <hip/hip_runtime.h>

#define BB 32
#define MM 512
#define SS 10
#define VV 32000
#define DD 128
#define HOPS 3
#define BM (BB * MM)
#define NREP 8   // u_num accumulation replicas (atomic contention spreading)

// ====================== PRIMARY PATH (histogram / dual-GEMV v2) ======================
// cu[b][v] and hist[b][v] are b-major for scatter locality.

// K1 gemv: cu[b][v] = dot(C_h[v,:], u_h[b,:]) for a 64-v tile; 4 waves, 8 b per wave.
// u_h staged on the fly: ubase + (sum_r unum_prev[r])/den_prev  (hop0: unum_prev null).
// Also: zeroes this hop's hist tile, den (block 0), unum replicas (blocks 0..31);
// block 0 writes materialized u_h to uwrite (if non-null).
__global__ __launch_bounds__(256) void gemv_k(const float* __restrict__ A,
                                              const float* __restrict__ ubase,
                                              const float* __restrict__ unum_prev,
                                              const float* __restrict__ den_prev,
                                              float* __restrict__ uwrite,
                                              float* __restrict__ cu,
                                              float* __restrict__ hist,
                                              float* __restrict__ den_this,
                                              float* __restrict__ unum_this) {
    __shared__ float us[BB * DD];        // 16 KB, linear
    __shared__ float As[64 * DD];        // 32 KB, quad-swizzled
    const int tid = threadIdx.x;
    const int v0 = blockIdx.x * 64;

    // ---- stage u_h (and materialize from block 0) ----
    for (int i = tid; i < BB * DD; i += 256) {
        float val = ubase[i];
        if (unum_prev) {
            float num = 0.f;
#pragma unroll
            for (int r = 0; r < NREP; ++r) num += unum_prev[r * BB * DD + i];
            val += num / den_prev[i >> 7];
        }
        us[i] = val;
        if (uwrite && blockIdx.x == 0) uwrite[i] = val;
    }

    // ---- stage A tile, coalesced global read, swizzled LDS write ----
    const float4* Ag = (const float4*)(A + (size_t)v0 * DD);
    float4* As4 = (float4*)As;
#pragma unroll
    for (int j = 0; j < 8; ++j) {
        const int f4 = j * 256 + tid;            // 0..2047
        const int v = f4 >> 5, q = f4 & 31;
        As4[(v << 5) | (q ^ (v & 31))] = Ag[f4];
    }

    // ---- zero hist tile: hist[b][v0..v0+64) ----
    const float4 z4 = make_float4(0.f, 0.f, 0.f, 0.f);
#pragma unroll
    for (int j = 0; j < 2; ++j) {
        const int e = j * 256 + tid;             // 0..511
        const int b = e >> 4, q = e & 15;
        *(float4*)(hist + (size_t)b * VV + v0 + q * 4) = z4;
    }
    // ---- zero den_this / unum_this ----
    if (blockIdx.x == 0 && tid < BB) den_this[tid] = 0.f;
    {
        const int i4 = blockIdx.x * 256 + tid;
        if (i4 < NREP * BB * DD / 4) ((float4*)unum_this)[i4] = z4;
    }
    __syncthreads();

    // ---- compute: lane owns row v0+lane (A in VGPRs), wave owns 8 b ----
    const int w = tid >> 6, lane = tid & 63;
    float4 a[32];
#pragma unroll
    for (int q = 0; q < 32; ++q)
        a[q] = As4[(lane << 5) | (q ^ (lane & 31))];

    const float4* us4 = (const float4*)us;
    const size_t gv = (size_t)v0 + lane;
    for (int bi = 0; bi < 8; ++bi) {
        const int b = w * 8 + bi;
        float p0 = 0.f, p1 = 0.f, p2 = 0.f, p3 = 0.f;
#pragma unroll
        for (int q = 0; q < 32; ++q) {
            const float4 u4 = us4[(b << 5) | q];   // wave-uniform broadcast
            p0 += a[q].x * u4.x;
            p1 += a[q].y * u4.y;
            p2 += a[q].z * u4.z;
            p3 += a[q].w * u4.w;
        }
        cu[(size_t)b * VV + gv] = (p0 + p1) + (p2 + p3);
    }
}

// K2 scatter: l = sum_s cu[b][tok]; e = exp(l) (max-free); atomics into hist[b][*], den[b].
template <int WRITE_LOGIT>
__global__ __launch_bounds__(256) void scatter_k(const int* __restrict__ story,
                                                 const float* __restrict__ cu,
                                                 float* __restrict__ hist,
                                                 float* __restrict__ den,
                                                 float* __restrict__ logit) {
    const int bm = blockIdx.x * 256 + threadIdx.x;
    const int b = bm >> 9;
    const int* st = story + (size_t)bm * SS;
    int tok[SS];
#pragma unroll
    for (int s = 0; s < SS; ++s) tok[s] = st[s];
    const float* cub = cu + (size_t)b * VV;
    float l = 0.f;
#pragma unroll
    for (int s = 0; s < SS; ++s) l += cub[tok[s]];
    if (WRITE_LOGIT) logit[bm] = l;
    const float e = expf(l);
    float* hb = hist + (size_t)b * VV;
#pragma unroll
    for (int s = 0; s < SS; ++s) unsafeAtomicAdd(&hb[tok[s]], e);
    float sv = e;
#pragma unroll
    for (int off = 32; off; off >>= 1) sv += __shfl_xor(sv, off, 64);
    if ((threadIdx.x & 63) == 0) unsafeAtomicAdd(&den[b], sv);
}

// K3 gemm: unum += sum_{v in 128-chunk} hist[v][b] * C[v][d].
// 4 waves own disjoint b-octets -> no cross-wave reduce; C read float2/lane (coalesced);
// h transposed into LDS, float4 broadcasts.
__global__ __launch_bounds__(256) void gemm_k(const float* __restrict__ Cn,
                                              const float* __restrict__ hist,
                                              float* __restrict__ unum) {
    __shared__ float hs[128 * BB];   // hs[vl][b], 16 KB
    const int tid = threadIdx.x;
    const int v0 = blockIdx.x * 128;

    // transposed stage: coalesced read of hist[b][v0..], LDS write hs[vl][b]
    {
        const int b = tid >> 3, vq = tid & 7;
#pragma unroll
        for (int j = 0; j < 4; ++j) {
            const int vbase = j * 32 + vq * 4;
            const float4 h4 = *(const float4*)(hist + (size_t)b * VV + v0 + vbase);
            hs[(vbase + 0) * BB + b] = h4.x;
            hs[(vbase + 1) * BB + b] = h4.y;
            hs[(vbase + 2) * BB + b] = h4.z;
            hs[(vbase + 3) * BB + b] = h4.w;
        }
    }
    __syncthreads();

    const int w = tid >> 6, lane = tid & 63;   // wave owns b in [w*8, w*8+8)
    float2 acc[8];
#pragma unroll
    for (int i = 0; i < 8; ++i) acc[i] = make_float2(0.f, 0.f);

    for (int vl = 0; vl < 128; ++vl) {
        const float2 c2 = ((const float2*)(Cn + (size_t)(v0 + vl) * DD))[lane];
        const float4* h4p = (const float4*)(hs + vl * BB);
        const float4 h0 = h4p[w * 2];        // b = w*8 .. w*8+3   (broadcast)
        const float4 h1 = h4p[w * 2 + 1];    // b = w*8+4 .. w*8+7 (broadcast)
        acc[0].x += h0.x * c2.x; acc[0].y += h0.x * c2.y;
        acc[1].x += h0.y * c2.x; acc[1].y += h0.y * c2.y;
        acc[2].x += h0.z * c2.x; acc[2].y += h0.z * c2.y;
        acc[3].x += h0.w * c2.x; acc[3].y += h0.w * c2.y;
        acc[4].x += h1.x * c2.x; acc[4].y += h1.x * c2.y;
        acc[5].x += h1.y * c2.x; acc[5].y += h1.y * c2.y;
        acc[6].x += h1.z * c2.x; acc[6].y += h1.z * c2.y;
        acc[7].x += h1.w * c2.x; acc[7].y += h1.w * c2.y;
    }
    float* dst = unum + (size_t)(blockIdx.x & (NREP - 1)) * (BB * DD);
#pragma unroll
    for (int bi = 0; bi < 8; ++bi) {
        float* p = dst + (size_t)(w * 8 + bi) * DD + 2 * lane;
        unsafeAtomicAdd(p, acc[bi].x);
        unsafeAtomicAdd(p + 1, acc[bi].y);
    }
}

// K4 final: uout = u2 + (sum_r unum2[r]) / den2
__global__ __launch_bounds__(256) void final_k(const float* __restrict__ u2,
                                               const float* __restrict__ unum2,
                                               const float* __restrict__ den2,
                                               float* __restrict__ uout) {
    const int i = blockIdx.x * 256 + threadIdx.x;
    if (i >= BB * DD) return;
    float num = 0.f;
#pragma unroll
    for (int r = 0; r < NREP; ++r) num += unum2[r * BB * DD + i];
    uout[i] = u2[i] + num / den2[i >> 7];
}

// ====================== FALLBACK PATH (round-1, known-good) ======================
__global__ __launch_bounds__(256) void init_u(const float* __restrict__ hidden,
                                              float* __restrict__ u) {
    int i = blockIdx.x * 256 + threadIdx.x;
    if (i < BB * DD) u[i] = hidden[i];
}

__global__ __launch_bounds__(256) void logit_kernel(const int* __restrict__ story,
                                                    const float* __restrict__ Ch,
                                                    const float* __restrict__ u,
                                                    float* __restrict__ logit) {
    int wid = (blockIdx.x * 256 + threadIdx.x) >> 6;
    int lane = threadIdx.x & 63;
    if (wid >= BB * MM) return;
    int b = wid >> 9;
    const int* st = story + (size_t)wid * SS;
    int tok[SS];
#pragma unroll
    for (int s = 0; s < SS; ++s) tok[s] = st[s];
    float ax = 0.f, ay = 0.f;
#pragma unroll
    for (int s = 0; s < SS; ++s) {
        const float2 v = ((const float2*)(Ch + (size_t)tok[s] * DD))[lane];
        ax += v.x; ay += v.y;
    }
    const float2 uv = ((const float2*)(u + b * DD))[lane];
    float p = ax * uv.x + ay * uv.y;
#pragma unroll
    for (int off = 32; off; off >>= 1) p += __shfl_down(p, off, 64);
    if (lane == 0) logit[wid] = p;
}

__global__ __launch_bounds__(256) void softmax_kernel(const float* __restrict__ logit,
                                                      float* __restrict__ prob) {
    int b = blockIdx.x;
    int t = threadIdx.x;
    __shared__ float red[8];
    float l0 = logit[b * MM + t];
    float l1 = logit[b * MM + 256 + t];
    float mx = fmaxf(l0, l1);
#pragma unroll
    for (int off = 32; off; off >>= 1) mx = fmaxf(mx, __shfl_xor(mx, off, 64));
    if ((t & 63) == 0) red[t >> 6] = mx;
    __syncthreads();
    mx = fmaxf(fmaxf(red[0], red[1]), fmaxf(red[2], red[3]));
    float e0 = expf(l0 - mx), e1 = expf(l1 - mx);
    float s = e0 + e1;
#pragma unroll
    for (int off = 32; off; off >>= 1) s += __shfl_xor(s, off, 64);
    if ((t & 63) == 0) red[4 + (t >> 6)] = s;
    __syncthreads();
    s = red[4] + red[5] + red[6] + red[7];
    float inv = 1.0f / s;
    prob[b * MM + t] = e0 * inv;
    prob[b * MM + 256 + t] = e1 * inv;
}

__global__ __launch_bounds__(256) void partial_kernel(const int* __restrict__ story,
                                                      const float* __restrict__ Ch1,
                                                      const float* __restrict__ prob,
                                                      float* __restrict__ partial,
                                                      int chunk) {
    int b = blockIdx.y, c = blockIdx.x;
    int w = threadIdx.x >> 6, lane = threadIdx.x & 63;
    int m0 = c * chunk;
    float ax = 0.f, ay = 0.f;
    for (int m = m0 + w; m < m0 + chunk; m += 4) {
        float pw = prob[b * MM + m];
        const int* st = story + (size_t)(b * MM + m) * SS;
        int tok[SS];
#pragma unroll
        for (int s = 0; s < SS; ++s) tok[s] = st[s];
        float sx = 0.f, sy = 0.f;
#pragma unroll
        for (int s = 0; s < SS; ++s) {
            const float2 v = ((const float2*)(Ch1 + (size_t)tok[s] * DD))[lane];
            sx += v.x; sy += v.y;
        }
        ax += pw * sx; ay += pw * sy;
    }
    __shared__ float redx[4][64];
    __shared__ float redy[4][64];
    redx[w][lane] = ax;
    redy[w][lane] = ay;
    __syncthreads();
    if (w == 0) {
        float ox = redx[0][lane] + redx[1][lane] + redx[2][lane] + redx[3][lane];
        float oy = redy[0][lane] + redy[1][lane] + redy[2][lane] + redy[3][lane];
        float2* dst = (float2*)(partial + ((size_t)b * gridDim.x + c) * DD);
        dst[lane] = make_float2(ox, oy);
    }
}

__global__ __launch_bounds__(256) void update_kernel(const float* __restrict__ partial,
                                                     float* __restrict__ u, int NC) {
    int i = blockIdx.x * 256 + threadIdx.x;
    if (i >= BB * DD) return;
    int b = i >> 7, d = i & 127;
    float s = 0.f;
    for (int c = 0; c < NC; ++c) s += partial[((size_t)b * NC + c) * DD + d];
    u[i] += s;
}

extern "C" void kernel_launch(void* const* d_in, const int* in_sizes, int n_in,
                              void* d_out, int out_size, void* d_ws, size_t ws_size,
                              hipStream_t stream) {
    const int*   story  = (const int*)d_in[0];
    const float* hidden = (const float*)d_in[1];
    const float* Cmat   = (const float*)d_in[2];

    float* out   = (float*)d_out;
    float* logit = out;              // final prob_logit [B,M]
    float* uout  = out + BB * MM;    // final u [B,D]

    // ws floats: cu | hist | unum[3][NREP*BB*DD] | den[3][BB] | u1 | u2
    const size_t szCU  = (size_t)BB * VV;
    const size_t szNUM = (size_t)NREP * BB * DD;
    const size_t need  = (2 * szCU + 3 * szNUM + 3 * BB + 2 * BB * DD) * sizeof(float);

    if (ws_size >= need) {
        float* cu   = (float*)d_ws;
        float* hist = cu + szCU;
        float* unum = hist + szCU;
        float* den  = unum + 3 * szNUM;
        float* u1   = den + 3 * BB;
        float* u2   = u1 + BB * DD;

        const float* C0 = Cmat;
        const float* C1 = Cmat + (size_t)1 * VV * DD;
        const float* C2 = Cmat + (size_t)2 * VV * DD;
        const float* C3 = Cmat + (size_t)3 * VV * DD;

        float* un0 = unum;
        float* un1 = unum + szNUM;
        float* un2 = unum + 2 * szNUM;
        float* dn0 = den, * dn1 = den + BB, * dn2 = den + 2 * BB;

        // hop 0
        gemv_k<<<VV / 64, 256, 0, stream>>>(C0, hidden, nullptr, nullptr, nullptr,
                                            cu, hist, dn0, un0);
        scatter_k<0><<<BM / 256, 256, 0, stream>>>(story, cu, hist, dn0, nullptr);
        gemm_k<<<VV / 128, 256, 0, stream>>>(C1, hist, un0);
        // hop 1 (gemv rebuilds u1 = hidden + un0/dn0, block 0 materializes it)
        gemv_k<<<VV / 64, 256, 0, stream>>>(C1, hidden, un0, dn0, u1,
                                            cu, hist, dn1, un1);
        scatter_k<0><<<BM / 256, 256, 0, stream>>>(story, cu, hist, dn1, nullptr);
        gemm_k<<<VV / 128, 256, 0, stream>>>(C2, hist, un1);
        // hop 2
        gemv_k<<<VV / 64, 256, 0, stream>>>(C2, u1, un1, dn1, u2,
                                            cu, hist, dn2, un2);
        scatter_k<1><<<BM / 256, 256, 0, stream>>>(story, cu, hist, dn2, logit);
        gemm_k<<<VV / 128, 256, 0, stream>>>(C3, hist, un2);
        final_k<<<(BB * DD + 255) / 256, 256, 0, stream>>>(u2, un2, dn2, uout);
    } else {
        float* prob = (float*)d_ws;
        int NC = 32;
        while (NC > 1 && (size_t)(BB * MM + BB * NC * DD) * 4 > ws_size) NC >>= 1;
        float* partial = prob + BB * MM;
        int chunk = MM / NC;

        init_u<<<(BB * DD + 255) / 256, 256, 0, stream>>>(hidden, uout);
        for (int h = 0; h < HOPS; ++h) {
            const float* Ca = Cmat + (size_t)h * VV * DD;
            const float* Cc = Cmat + (size_t)(h + 1) * VV * DD;
            logit_kernel<<<(BB * MM) / 4, 256, 0, stream>>>(story, Ca, uout, logit);
            softmax_kernel<<<BB, 256, 0, stream>>>(logit, prob);
            partial_kernel<<<dim3(NC, BB), 256, 0, stream>>>(story, Cc, prob, partial, chunk);
            update_kernel<<<(BB * DD + 255) / 256, 256, 0, stream>>>(partial, uout, NC);
        }
    }
}

// Round 7
// 66.104 us; speedup vs baseline: 2.8785x; 2.8785x over previous
//
#include <hip/hip_runtime.h>

#define BB 32
#define MM 512
#define SS 10
#define VV 32000
#define DD 128
#define HOPS 3
#define BM (BB * MM)
#define NCHUNK 32          // chunks per b in hop kernels
#define CHM (MM / NCHUNK)  // 16 m per chunk -> 4 m per wave
#define PSTRIDE 132        // partial row: 128 num + 1 den + pad

// bf16 helpers (exact unpack; RN pack)
__device__ __forceinline__ unsigned bfrn(float f) {
    unsigned u = __float_as_uint(f);
    return (u + 0x7FFFu + ((u >> 16) & 1u)) >> 16;
}
__device__ __forceinline__ float bflo(unsigned q) {   // low bf16 of packed pair
    return __uint_as_float(q << 16);
}
__device__ __forceinline__ float bfhi(unsigned q) {   // high bf16
    return __uint_as_float(q & 0xFFFF0000u);
}

// ====================== PRIMARY PATH (bf16 tables + 4 fused hops) ======================

// K0: dense f32 -> bf16 conversion of all 4 tables. 8 elems/thread.
__global__ __launch_bounds__(256) void cvt_bf16(const float* __restrict__ C,
                                                unsigned* __restrict__ Cb /* packed pairs */) {
    const int gid = blockIdx.x * 256 + threadIdx.x;       // 0 .. 2,047,999
    const float4 f0 = ((const float4*)C)[gid * 2];
    const float4 f1 = ((const float4*)C)[gid * 2 + 1];
    uint4 o;
    o.x = bfrn(f0.x) | (bfrn(f0.y) << 16);
    o.y = bfrn(f0.z) | (bfrn(f0.w) << 16);
    o.z = bfrn(f1.x) | (bfrn(f1.y) << 16);
    o.w = bfrn(f1.z) | (bfrn(f1.w) << 16);
    ((uint4*)Cb)[gid] = o;
}

// Shared hop body pieces. Grid dim3(NCHUNK, BB), 256 threads (4 waves).
// Max-free softmax partials: P row = [num[128] | den].
// HOP0: logit from gather(C0b), out from gather(C1b) (writes E1), uprev=hidden, no pin.
// HOP1: logit from E1, out from gather(C2b) (writes E2), u rebuilt from hidden+P0; c==0 writes u1.
// HOP2: logit from E2 (writes final logit), out from gather(C3b), u from u1+P1; c==0 writes u2.
template <int HOP>
__global__ __launch_bounds__(256) void hop_k(const int* __restrict__ story,
                                             const unsigned* __restrict__ Clog, // bf16 pairs (HOP0) else null
                                             const unsigned* __restrict__ Cout, // bf16 pairs gather table
                                             const float* __restrict__ Elog,    // f32 E for logits (HOP>0)
                                             float* __restrict__ Eout,          // f32 E written (HOP<2)
                                             const float* __restrict__ uprev,
                                             const float* __restrict__ pin,
                                             const float* __restrict__ den_in_unused,
                                             float* __restrict__ uwrite,
                                             float* __restrict__ logit,
                                             float* __restrict__ pout) {
    const int b = blockIdx.y, c = blockIdx.x;
    const int tid = threadIdx.x;
    const int w = tid >> 6, lane = tid & 63;

    __shared__ float su[DD];
    if (tid < DD) {
        float v = uprev[b * DD + tid];
        if (HOP > 0) {
            float num = 0.f, dsum = 0.f;
            for (int cc = 0; cc < NCHUNK; ++cc) {
                const float* p = pin + ((size_t)b * NCHUNK + cc) * PSTRIDE;
                num += p[tid];
                dsum += p[DD];
            }
            v += num / dsum;
            if (c == 0) uwrite[b * DD + tid] = v;
        }
        su[tid] = v;
    }
    __syncthreads();
    const float2 uv = ((const float2*)su)[lane];

    float nx = 0.f, ny = 0.f, den = 0.f;
#pragma unroll
    for (int k = 0; k < CHM / 4; ++k) {
        const int m = c * CHM + k * 4 + w;
        const int bm = b * MM + m;
        int tok[SS];
        const int* st = story + (size_t)bm * SS;
#pragma unroll
        for (int s = 0; s < SS; ++s) tok[s] = st[s];

        // ---- logit ----
        float ex, ey;
        if (HOP == 0) {
            ex = 0.f; ey = 0.f;
#pragma unroll
            for (int s = 0; s < SS; ++s) {
                const unsigned q = (Clog + (size_t)tok[s] * (DD / 2))[lane];
                ex += bflo(q); ey += bfhi(q);
            }
        } else {
            const float2 v = ((const float2*)(Elog + (size_t)bm * DD))[lane];
            ex = v.x; ey = v.y;
        }
        float l = ex * uv.x + ey * uv.y;
#pragma unroll
        for (int off = 32; off; off >>= 1) l += __shfl_xor(l, off, 64);
        if (HOP == 2 && lane == 0) logit[bm] = l;
        const float e = expf(l);

        // ---- output row (gather bf16) ----
        float rx = 0.f, ry = 0.f;
#pragma unroll
        for (int s = 0; s < SS; ++s) {
            const unsigned q = (Cout + (size_t)tok[s] * (DD / 2))[lane];
            rx += bflo(q); ry += bfhi(q);
        }
        if (HOP < 2)
            ((float2*)(Eout + (size_t)bm * DD))[lane] = make_float2(rx, ry);
        nx += e * rx; ny += e * ry; den += e;
    }

    __shared__ float sx[4][64], sy[4][64], sd[4];
    sx[w][lane] = nx; sy[w][lane] = ny;
    if (lane == 0) sd[w] = den;
    __syncthreads();
    if (w == 0) {
        const float ox = sx[0][lane] + sx[1][lane] + sx[2][lane] + sx[3][lane];
        const float oy = sy[0][lane] + sy[1][lane] + sy[2][lane] + sy[3][lane];
        float* prow = pout + ((size_t)b * NCHUNK + c) * PSTRIDE;
        ((float2*)prow)[lane] = make_float2(ox, oy);
        if (lane == 0) prow[DD] = sd[0] + sd[1] + sd[2] + sd[3];
    }
}

// final: uout = u2 + red(P2)
__global__ __launch_bounds__(128) void final_u(const float* __restrict__ pin,
                                               const float* __restrict__ u2,
                                               float* __restrict__ uout) {
    const int b = blockIdx.x, d = threadIdx.x;
    float num = 0.f, den = 0.f;
    for (int cc = 0; cc < NCHUNK; ++cc) {
        const float* p = pin + ((size_t)b * NCHUNK + cc) * PSTRIDE;
        num += p[d];
        den += p[DD];
    }
    uout[b * DD + d] = u2[b * DD + d] + num / den;
}

// ====================== FALLBACK PATH (round-1, known-good) ======================
__global__ __launch_bounds__(256) void init_u(const float* __restrict__ hidden,
                                              float* __restrict__ u) {
    int i = blockIdx.x * 256 + threadIdx.x;
    if (i < BB * DD) u[i] = hidden[i];
}

__global__ __launch_bounds__(256) void logit_kernel(const int* __restrict__ story,
                                                    const float* __restrict__ Ch,
                                                    const float* __restrict__ u,
                                                    float* __restrict__ logit) {
    int wid = (blockIdx.x * 256 + threadIdx.x) >> 6;
    int lane = threadIdx.x & 63;
    if (wid >= BB * MM) return;
    int b = wid >> 9;
    const int* st = story + (size_t)wid * SS;
    int tok[SS];
#pragma unroll
    for (int s = 0; s < SS; ++s) tok[s] = st[s];
    float ax = 0.f, ay = 0.f;
#pragma unroll
    for (int s = 0; s < SS; ++s) {
        const float2 v = ((const float2*)(Ch + (size_t)tok[s] * DD))[lane];
        ax += v.x; ay += v.y;
    }
    const float2 uv = ((const float2*)(u + b * DD))[lane];
    float p = ax * uv.x + ay * uv.y;
#pragma unroll
    for (int off = 32; off; off >>= 1) p += __shfl_down(p, off, 64);
    if (lane == 0) logit[wid] = p;
}

__global__ __launch_bounds__(256) void softmax_kernel(const float* __restrict__ logit,
                                                      float* __restrict__ prob) {
    int b = blockIdx.x;
    int t = threadIdx.x;
    __shared__ float red[8];
    float l0 = logit[b * MM + t];
    float l1 = logit[b * MM + 256 + t];
    float mx = fmaxf(l0, l1);
#pragma unroll
    for (int off = 32; off; off >>= 1) mx = fmaxf(mx, __shfl_xor(mx, off, 64));
    if ((t & 63) == 0) red[t >> 6] = mx;
    __syncthreads();
    mx = fmaxf(fmaxf(red[0], red[1]), fmaxf(red[2], red[3]));
    float e0 = expf(l0 - mx), e1 = expf(l1 - mx);
    float s = e0 + e1;
#pragma unroll
    for (int off = 32; off; off >>= 1) s += __shfl_xor(s, off, 64);
    if ((t & 63) == 0) red[4 + (t >> 6)] = s;
    __syncthreads();
    s = red[4] + red[5] + red[6] + red[7];
    float inv = 1.0f / s;
    prob[b * MM + t] = e0 * inv;
    prob[b * MM + 256 + t] = e1 * inv;
}

__global__ __launch_bounds__(256) void partial_kernel(const int* __restrict__ story,
                                                      const float* __restrict__ Ch1,
                                                      const float* __restrict__ prob,
                                                      float* __restrict__ partial,
                                                      int chunk) {
    int b = blockIdx.y, c = blockIdx.x;
    int w = threadIdx.x >> 6, lane = threadIdx.x & 63;
    int m0 = c * chunk;
    float ax = 0.f, ay = 0.f;
    for (int m = m0 + w; m < m0 + chunk; m += 4) {
        float pw = prob[b * MM + m];
        const int* st = story + (size_t)(b * MM + m) * SS;
        int tok[SS];
#pragma unroll
        for (int s = 0; s < SS; ++s) tok[s] = st[s];
        float sx = 0.f, sy = 0.f;
#pragma unroll
        for (int s = 0; s < SS; ++s) {
            const float2 v = ((const float2*)(Ch1 + (size_t)tok[s] * DD))[lane];
            sx += v.x; sy += v.y;
        }
        ax += pw * sx; ay += pw * sy;
    }
    __shared__ float redx[4][64];
    __shared__ float redy[4][64];
    redx[w][lane] = ax;
    redy[w][lane] = ay;
    __syncthreads();
    if (w == 0) {
        float ox = redx[0][lane] + redx[1][lane] + redx[2][lane] + redx[3][lane];
        float oy = redy[0][lane] + redy[1][lane] + redy[2][lane] + redy[3][lane];
        float2* dst = (float2*)(partial + ((size_t)b * gridDim.x + c) * DD);
        dst[lane] = make_float2(ox, oy);
    }
}

__global__ __launch_bounds__(256) void update_kernel(const float* __restrict__ partial,
                                                     float* __restrict__ u, int NC) {
    int i = blockIdx.x * 256 + threadIdx.x;
    if (i >= BB * DD) return;
    int b = i >> 7, d = i & 127;
    float s = 0.f;
    for (int c = 0; c < NC; ++c) s += partial[((size_t)b * NC + c) * DD + d];
    u[i] += s;
}

extern "C" void kernel_launch(void* const* d_in, const int* in_sizes, int n_in,
                              void* d_out, int out_size, void* d_ws, size_t ws_size,
                              hipStream_t stream) {
    const int*   story  = (const int*)d_in[0];
    const float* hidden = (const float*)d_in[1];
    const float* Cmat   = (const float*)d_in[2];

    float* out   = (float*)d_out;
    float* logit = out;              // final prob_logit [B,M]
    float* uout  = out + BB * MM;    // final u [B,D]

    // ws layout (float words): Cb (bf16, 4*VV*DD/2 words) | E1 | E2 | P0 P1 P2 | u1 u2
    const size_t szCb = (size_t)4 * VV * DD / 2;       // 8.192M words
    const size_t szE  = (size_t)BM * DD;               // 2.097M
    const size_t szP  = (size_t)BB * NCHUNK * PSTRIDE; // 135K
    const size_t need = (szCb + 2 * szE + 3 * szP + 2 * BB * DD) * sizeof(float);

    if (ws_size >= need) {
        unsigned* Cb = (unsigned*)d_ws;
        float* E1 = (float*)d_ws + szCb;
        float* E2 = E1 + szE;
        float* P0 = E2 + szE;
        float* P1 = P0 + szP;
        float* P2 = P1 + szP;
        float* u1 = P2 + szP;
        float* u2 = u1 + BB * DD;

        const unsigned* C0b = Cb;
        const unsigned* C1b = Cb + (size_t)1 * VV * DD / 2;
        const unsigned* C2b = Cb + (size_t)2 * VV * DD / 2;
        const unsigned* C3b = Cb + (size_t)3 * VV * DD / 2;

        cvt_bf16<<<(4 * VV * DD / 8) / 256, 256, 0, stream>>>(Cmat, Cb);

        hop_k<0><<<dim3(NCHUNK, BB), 256, 0, stream>>>(
            story, C0b, C1b, nullptr, E1, hidden, nullptr, nullptr, nullptr, nullptr, P0);
        hop_k<1><<<dim3(NCHUNK, BB), 256, 0, stream>>>(
            story, nullptr, C2b, E1, E2, hidden, P0, nullptr, u1, nullptr, P1);
        hop_k<2><<<dim3(NCHUNK, BB), 256, 0, stream>>>(
            story, nullptr, C3b, E2, nullptr, u1, P1, nullptr, u2, logit, P2);
        final_u<<<BB, 128, 0, stream>>>(P2, u2, uout);
    } else {
        float* prob = (float*)d_ws;
        int NC = 32;
        while (NC > 1 && (size_t)(BB * MM + BB * NC * DD) * 4 > ws_size) NC >>= 1;
        float* partial = prob + BB * MM;
        int chunk = MM / NC;

        init_u<<<(BB * DD + 255) / 256, 256, 0, stream>>>(hidden, uout);
        for (int h = 0; h < HOPS; ++h) {
            const float* Ca = Cmat + (size_t)h * VV * DD;
            const float* Cc = Cmat + (size_t)(h + 1) * VV * DD;
            logit_kernel<<<(BB * MM) / 4, 256, 0, stream>>>(story, Ca, uout, logit);
            softmax_kernel<<<BB, 256, 0, stream>>>(logit, prob);
            partial_kernel<<<dim3(NC, BB), 256, 0, stream>>>(story, Cc, prob, partial, chunk);
            update_kernel<<<(BB * DD + 255) / 256, 256, 0, stream>>>(partial, uout, NC);
        }
    }
}